// Round 10
// baseline (284.840 us; speedup 1.0000x reference)
//
#include <hip/hip_runtime.h>
#include <hip/hip_bf16.h>

typedef __hip_bfloat16 bf16;
typedef __attribute__((ext_vector_type(8))) short short8v;
typedef __attribute__((ext_vector_type(4))) short short4v;
typedef __attribute__((ext_vector_type(4))) float f32x4;

#define MFMA_16x16x32(a, b, c) __builtin_amdgcn_mfma_f32_16x16x32_bf16((a), (b), (c), 0, 0, 0)

constexpr int Bc = 2, Sc = 2048, DMc = 2048, Hc = 16, DLc = 512, DHc = 128;

__device__ __forceinline__ void gload_lds16(const bf16* g, void* lds) {
  __builtin_amdgcn_global_load_lds(
      (const __attribute__((address_space(1))) void*)g,
      (__attribute__((address_space(3))) void*)lds, 16, 0, 0);
}

__device__ __forceinline__ unsigned short bf16bits(float f) {
  return __builtin_bit_cast(unsigned short, __float2bfloat16(f));
}

__device__ __forceinline__ float bf16tof(unsigned short u) {
  unsigned int x = ((unsigned int)u) << 16;
  return __builtin_bit_cast(float, x);
}

// ---------------------------------------------------------------------------
// fp32 -> bf16 conversion over 6 segments, one launch
// ---------------------------------------------------------------------------
struct CvtArgs {
  const float* src[6];
  bf16* dst[6];
  unsigned int cum[6];     // cumulative start (in 4-elem chunks)
  unsigned int total4;
};

__global__ __launch_bounds__(256) void cvt_all_kernel(CvtArgs a)
{
  unsigned int i = blockIdx.x * 256 + threadIdx.x;
  const unsigned int stride = gridDim.x * 256;
  for (; i < a.total4; i += stride) {
    int s = 0;
#pragma unroll
    for (int k = 1; k < 6; ++k) s += (i >= a.cum[k]) ? 1 : 0;
    unsigned int off = (i - a.cum[s]) * 4;
    float4 v = *(const float4*)(a.src[s] + off);
    short4v p;
    p[0] = (short)bf16bits(v.x);
    p[1] = (short)bf16bits(v.y);
    p[2] = (short)bf16bits(v.z);
    p[3] = (short)bf16bits(v.w);
    *(short4v*)(a.dst[s] + off) = p;
  }
}

// ---------------------------------------------------------------------------
// Generic 128x128 tile GEMM, BK=32, C = A * BT^T. EPI: 0 bf16 C, 1 bf16 C^T,
// 2 fp32 C.
// ---------------------------------------------------------------------------
template<int EPI>
__device__ __forceinline__ void gemm_tile_128(
    const bf16* __restrict__ A, const bf16* __restrict__ BT, void* __restrict__ Cv,
    int K, int ldc, int row0, int col0, bf16* As, bf16* Bs)
{
  const int tid = threadIdx.x;
  const int lane = tid & 63, wid = tid >> 6;
  const int wr = wid >> 1, wc = wid & 1;

  f32x4 acc[4][4] = {};

  const int srow = tid >> 2;
  const int scol = (tid & 3) * 8;
  const bf16* Ag = A + (size_t)(row0 + srow) * K + scol;
  const bf16* Bg = BT + (size_t)(col0 + srow) * K + scol;
  char* AsW = (char*)As + wid * 1024;
  char* BsW = (char*)Bs + wid * 1024;

  const int fr = lane & 15, fk = (lane >> 4) * 8;
  const bf16* aRd = As + (wr * 64 + fr) * 32 + fk;
  const bf16* bRd = Bs + (wc * 64 + fr) * 32 + fk;

  for (int k0 = 0; k0 < K; k0 += 32) {
    gload_lds16(Ag, AsW);
    gload_lds16(Ag + (size_t)64 * K, AsW + 4096);
    gload_lds16(Bg, BsW);
    gload_lds16(Bg + (size_t)64 * K, BsW + 4096);
    Ag += 32; Bg += 32;
    __syncthreads();
    short8v a[4], b[4];
#pragma unroll
    for (int m = 0; m < 4; ++m) a[m] = *(const short8v*)(aRd + m * 16 * 32);
#pragma unroll
    for (int n = 0; n < 4; ++n) b[n] = *(const short8v*)(bRd + n * 16 * 32);
#pragma unroll
    for (int m = 0; m < 4; ++m)
#pragma unroll
      for (int n = 0; n < 4; ++n)
        acc[m][n] = MFMA_16x16x32(a[m], b[n], acc[m][n]);
    __syncthreads();
  }

  const int crow = (lane >> 4) * 4, ccol = lane & 15;
  if (EPI == 0) {
    bf16* C = (bf16*)Cv;
#pragma unroll
    for (int m = 0; m < 4; ++m)
#pragma unroll
      for (int n = 0; n < 4; ++n) {
        bf16* Cp = C + (size_t)(row0 + wr * 64 + m * 16 + crow) * ldc
                     + col0 + wc * 64 + n * 16 + ccol;
#pragma unroll
        for (int r = 0; r < 4; ++r)
          Cp[(size_t)r * ldc] = __float2bfloat16(acc[m][n][r]);
      }
  } else if (EPI == 1) {
    bf16* C = (bf16*)Cv;
#pragma unroll
    for (int m = 0; m < 4; ++m)
#pragma unroll
      for (int n = 0; n < 4; ++n) {
        short4v pk;
#pragma unroll
        for (int r = 0; r < 4; ++r)
          pk[r] = (short)bf16bits(acc[m][n][r]);
        bf16* Cp = C + (size_t)(col0 + wc * 64 + n * 16 + ccol) * ldc
                     + row0 + wr * 64 + m * 16 + crow;
        *(short4v*)Cp = pk;
      }
  } else {
    float* C = (float*)Cv;
#pragma unroll
    for (int m = 0; m < 4; ++m)
#pragma unroll
      for (int n = 0; n < 4; ++n) {
        float* Cp = C + (size_t)(row0 + wr * 64 + m * 16 + crow) * ldc
                      + col0 + wc * 64 + n * 16 + ccol;
#pragma unroll
        for (int r = 0; r < 4; ++r)
          Cp[(size_t)r * ldc] = acc[m][n][r];
      }
  }
}

template<int EPI>
__global__ __launch_bounds__(256) void gemm_bt_kernel(
    const bf16* __restrict__ A, const bf16* __restrict__ BT, void* __restrict__ C,
    int K, int N)
{
  __shared__ bf16 As[128 * 32];
  __shared__ bf16 Bs[128 * 32];
  gemm_tile_128<EPI>(A, BT, C, K, N, blockIdx.y * 128, blockIdx.x * 128, As, Bs);
}

// Fused Q-proj + KV-down: N = 2048 (Wq) + 512 (Wdkv), K = 2048.
__global__ __launch_bounds__(256) void qkv_gemm_kernel(
    const bf16* __restrict__ xb, const bf16* __restrict__ Wqb,
    const bf16* __restrict__ Wdkvb, bf16* __restrict__ Qb, bf16* __restrict__ Ck)
{
  __shared__ bf16 As[128 * 32];
  __shared__ bf16 Bs[128 * 32];
  const int bx = blockIdx.x, row0 = blockIdx.y * 128;
  if (bx < 16)
    gemm_tile_128<0>(xb, Wqb, Qb, DMc, DMc, row0, bx * 128, As, Bs);
  else
    gemm_tile_128<0>(xb, Wdkvb, Ck, DMc, DLc, row0, (bx - 16) * 128, As, Bs);
}

// Fused K-up + V-up as ONE GEMM over stacked heads.
__global__ __launch_bounds__(256) void up_gemm_kernel(
    const bf16* __restrict__ Ck, const bf16* __restrict__ Wukb,
    const bf16* __restrict__ Wuvb, bf16* __restrict__ Kcat, bf16* __restrict__ VTcat)
{
  __shared__ bf16 As[128 * 32];
  __shared__ bf16 Bs[128 * 32];
  const int bx = blockIdx.x, row0 = blockIdx.y * 128;
  if (bx < 16)
    gemm_tile_128<0>(Ck, Wukb, Kcat, DLc, DMc, row0, bx * 128, As, Bs);
  else
    gemm_tile_128<1>(Ck, Wuvb, VTcat, DLc, Bc * Sc, row0, (bx - 16) * 128, As, Bs);
}

// ---------------------------------------------------------------------------
// Flash attention with KV-split. LDS trimmed to 72 KB (< half of 160 KB) so
// TWO blocks co-reside per CU: K/V dbuf 64 KB + per-wave 1 KB P-quarter
// buffers (8 KB). P roundtrip runs in quarters (mi x tf); quarter layout is
// [8 rows][128 B] with row' = row&7, half = row>>3 folded into columns and
// byte ^= (row&7)<<4 swizzle (write banks spread, b128 reads aligned).
// launch_bounds (512,2): 104-VGPR compile; (512,4) spilled (r8).
// ---------------------------------------------------------------------------
constexpr int KVB = 64;
constexpr int NSPL = 2;
constexpr int NTT2 = Sc / NSPL / KVB;   // 16 tiles per split
constexpr int VSTR = Bc * Sc;           // 4096

__global__ __launch_bounds__(512, 2) void mla_attn_kernel(
    const bf16* __restrict__ Q, const bf16* __restrict__ Kcat,
    const bf16* __restrict__ VTcat,
    bf16* __restrict__ Op0, bf16* __restrict__ Op1,
    float* __restrict__ ml0, float* __restrict__ ml1)
{
  __shared__ bf16 Ks[2][KVB * DHc];    // 16 KB each
  __shared__ bf16 Vs[2][DHc * KVB];    // 16 KB each
  __shared__ bf16 Pl[8][512];          // per-wave 1 KB P-quarter buffer (8 KB)

  const int tid = threadIdx.x, lane = tid & 63, wid = tid >> 6;
  const int h = blockIdx.y;
  const int b = blockIdx.z >> 1, spl = blockIdx.z & 1;
  const int q0 = blockIdx.x * 256 + wid * 32;
  const int fr = lane & 15, fg = lane >> 4;
  const int tbase = spl * (Sc / NSPL);

  bf16* Po = spl ? Op1 : Op0;
  float* mlp = spl ? ml1 : ml0;

  const bf16* Qp = Q + (size_t)(b * Sc + q0 + fr) * DMc + h * DHc + fg * 8;
  short8v qf[2][4];
#pragma unroll
  for (int mi = 0; mi < 2; ++mi)
#pragma unroll
    for (int kf = 0; kf < 4; ++kf)
      qf[mi][kf] = *(const short8v*)(Qp + (size_t)mi * 16 * DMc + kf * 32);

  const bf16* Kb = Kcat + (size_t)b * Sc * DMc + h * DHc;      // K[t][d], stride DMc
  const bf16* Vb = VTcat + (size_t)(h * DHc) * VSTR + b * Sc;  // VT[d][t], stride VSTR

  // staging addresses (inverse-swizzled global sources; LDS dest linear)
  const int krow = wid * 4 + fg;
  const int kcolB = (fr * 16) ^ ((krow & 7) << 4);
  const bf16* kp = Kb + (size_t)(krow + tbase) * DMc + (kcolB >> 1);
  const int vrow = wid * 8 + (lane >> 3);
  const int vcolB = ((lane & 7) * 16) ^ ((lane >> 3) << 4);
  const bf16* vp = Vb + (size_t)vrow * VSTR + (vcolB >> 1) + tbase;

  auto STAGE = [&](int buf) {
    char* kd = (char*)(&Ks[buf][0]) + wid * 1024;
    gload_lds16(kp, kd);
    gload_lds16(kp + (size_t)32 * DMc, kd + 8192);
    char* vd = (char*)(&Vs[buf][0]) + wid * 1024;
    gload_lds16(vp, vd);
    gload_lds16(vp + (size_t)64 * VSTR, vd + 8192);
    kp += (size_t)KVB * DMc;
    vp += KVB;
  };

  f32x4 oacc[2][8] = {};
  float m_r[2][4], l_r[2][4], msc[2][4];
#pragma unroll
  for (int mi = 0; mi < 2; ++mi)
#pragma unroll
    for (int r = 0; r < 4; ++r) {
      m_r[mi][r] = -1e30f; l_r[mi][r] = 0.f; msc[mi][r] = -1e30f;
    }
  const float SCL2 = 0.12751650f;     // (1/sqrt(128)) * log2(e)
  const float THRraw = 47.0f;         // ~6 / SCL2 -> p bounded by 2^6

  STAGE(0);
  int cur = 0;
  char* Pw = (char*)(&Pl[wid][0]);

  for (int it = 0; it < NTT2; ++it) {
    asm volatile("s_waitcnt vmcnt(0)" ::: "memory");
    __builtin_amdgcn_s_barrier();
    asm volatile("" ::: "memory");
    if (it + 1 < NTT2) STAGE(cur ^ 1);   // overwrite: safe, all waves past barrier
    asm volatile("" ::: "memory");

    // ---- QK^T ----
    f32x4 sacc[2][4] = {};
    __builtin_amdgcn_s_setprio(1);
#pragma unroll
    for (int nf = 0; nf < 4; ++nf) {
#pragma unroll
      for (int kf = 0; kf < 4; ++kf) {
        const bf16* kr = &Ks[cur][(nf * 16 + fr) * 128 +
                                  (((kf * 64 + fg * 16) ^ ((fr & 7) << 4)) >> 1)];
        short8v kfrag = *(const short8v*)kr;
        sacc[0][nf] = MFMA_16x16x32(qf[0][kf], kfrag, sacc[0][nf]);
        sacc[1][nf] = MFMA_16x16x32(qf[1][kf], kfrag, sacc[1][nf]);
      }
    }
    __builtin_amdgcn_s_setprio(0);

    // ---- online softmax with defer-max ----
    float pmax[2][4];
    float dmax = -1e30f;
#pragma unroll
    for (int mi = 0; mi < 2; ++mi)
#pragma unroll
      for (int r = 0; r < 4; ++r) {
        pmax[mi][r] = fmaxf(fmaxf(sacc[mi][0][r], sacc[mi][1][r]),
                            fmaxf(sacc[mi][2][r], sacc[mi][3][r]));
        dmax = fmaxf(dmax, pmax[mi][r] - m_r[mi][r]);
      }

    if (!__all(dmax <= THRraw)) {
#pragma unroll
      for (int mi = 0; mi < 2; ++mi) {
        f32x4 corrv;
#pragma unroll
        for (int r = 0; r < 4; ++r) {
          float red = pmax[mi][r];
#pragma unroll
          for (int mk = 1; mk < 16; mk <<= 1)
            red = fmaxf(red, __shfl_xor(red, mk, 64));
          float mnew = fmaxf(m_r[mi][r], red);
          float c = exp2f((m_r[mi][r] - mnew) * SCL2);
          m_r[mi][r] = mnew;
          msc[mi][r] = mnew * SCL2;
          l_r[mi][r] *= c;
          corrv[r] = c;
        }
#pragma unroll
        for (int df = 0; df < 8; ++df) oacc[mi][df] *= corrv;
      }
    }

    // ---- P compute + quarter LDS roundtrips (per-wave private 1 KB) ----
    short8v pa[2][2];
#pragma unroll
    for (int mi = 0; mi < 2; ++mi) {
#pragma unroll
      for (int tf = 0; tf < 2; ++tf) {
#pragma unroll
        for (int nfl = 0; nfl < 2; ++nfl) {
          const int nf = tf * 2 + nfl;
#pragma unroll
          for (int r = 0; r < 4; ++r) {
            float p = exp2f(__builtin_fmaf(sacc[mi][nf][r], SCL2, -msc[mi][r]));
            l_r[mi][r] += p;
            const int row = fg * 4 + r;                 // 0..15
            const int rp = row & 7;
            const int cb = (((row >> 3) * 64) + nfl * 32 + fr * 2) ^ (rp << 4);
            *(bf16*)(Pw + rp * 128 + cb) = __float2bfloat16(p);
          }
        }
        asm volatile("s_waitcnt lgkmcnt(0)" ::: "memory");
        __builtin_amdgcn_sched_barrier(0);
        const int rb = (fr & 7) * 128 +
                       ((((fr >> 3) * 64) + fg * 16) ^ ((fr & 7) << 4));
        pa[mi][tf] = *(const short8v*)(Pw + rb);
        __builtin_amdgcn_sched_barrier(0);
      }
    }

    // ---- PV ----
    __builtin_amdgcn_s_setprio(1);
#pragma unroll
    for (int tf = 0; tf < 2; ++tf) {
#pragma unroll
      for (int df = 0; df < 8; ++df) {
        const bf16* vr = &Vs[cur][(df * 16 + fr) * 64 +
                                  (((tf * 64 + fg * 16) ^ ((fr & 7) << 4)) >> 1)];
        short8v vfrag = *(const short8v*)vr;
        oacc[0][df] = MFMA_16x16x32(pa[0][tf], vfrag, oacc[0][df]);
        oacc[1][df] = MFMA_16x16x32(pa[1][tf], vfrag, oacc[1][df]);
      }
    }
    __builtin_amdgcn_s_setprio(0);

    cur ^= 1;
  }

  // epilogue: reduce l, store (m, l) + unnormalized O
#pragma unroll
  for (int mi = 0; mi < 2; ++mi) {
    float lred[4];
#pragma unroll
    for (int r = 0; r < 4; ++r) {
      float l = l_r[mi][r];
#pragma unroll
      for (int mk = 1; mk < 16; mk <<= 1)
        l += __shfl_xor(l, mk, 64);
      lred[r] = l;
    }
    if (fr == 0) {
#pragma unroll
      for (int r = 0; r < 4; ++r) {
        int idx = (b * Hc + h) * Sc + q0 + mi * 16 + fg * 4 + r;
        *(float2*)(mlp + 2 * idx) = make_float2(m_r[mi][r], lred[r]);
      }
    }
    bf16* Pp = Po + (size_t)(b * Sc + q0 + mi * 16 + fg * 4) * DMc + h * DHc + fr;
#pragma unroll
    for (int df = 0; df < 8; ++df)
#pragma unroll
      for (int r = 0; r < 4; ++r)
        Pp[(size_t)r * DMc + df * 16] = __float2bfloat16(oacc[mi][df][r]);
  }
}

// ---------------------------------------------------------------------------
// Combine: AO = (w0*O0 + w1*O1) / (w0*l0 + w1*l1), w_s = exp2((m_s-M)*SCL2).
// ---------------------------------------------------------------------------
__global__ __launch_bounds__(256) void attn_combine_kernel(
    const bf16* __restrict__ Op0, const bf16* __restrict__ Op1,
    const float* __restrict__ ml0, const float* __restrict__ ml1,
    bf16* __restrict__ AO)
{
  const float SCL2 = 0.12751650f;
  int idx = blockIdx.x * 256 + threadIdx.x;     // chunk of 8 bf16
  int col8 = idx & (DMc / 8 - 1);
  int row = idx >> 8;
  int h = col8 >> 4;
  int b = row >> 11, q = row & (Sc - 1);
  int mlIdx = ((b * Hc + h) * Sc + q) * 2;
  float m0 = ml0[mlIdx], l0 = ml0[mlIdx + 1];
  float m1 = ml1[mlIdx], l1 = ml1[mlIdx + 1];
  float M = fmaxf(m0, m1);
  float w0 = exp2f((m0 - M) * SCL2), w1 = exp2f((m1 - M) * SCL2);
  float inv = 1.f / (w0 * l0 + w1 * l1);
  w0 *= inv; w1 *= inv;
  short8v a0 = *(const short8v*)(Op0 + (size_t)idx * 8);
  short8v a1 = *(const short8v*)(Op1 + (size_t)idx * 8);
  short8v o;
#pragma unroll
  for (int j = 0; j < 8; ++j) {
    float v = w0 * bf16tof((unsigned short)a0[j]) + w1 * bf16tof((unsigned short)a1[j]);
    o[j] = (short)bf16bits(v);
  }
  *(short8v*)(AO + (size_t)idx * 8) = o;
}

// ---------------------------------------------------------------------------
extern "C" void kernel_launch(void* const* d_in, const int* in_sizes, int n_in,
                              void* d_out, int out_size, void* d_ws, size_t ws_size,
                              hipStream_t stream)
{
  const float* x    = (const float*)d_in[0];
  const float* Wq   = (const float*)d_in[1];
  const float* Wdkv = (const float*)d_in[2];
  const float* Wuk  = (const float*)d_in[3];
  const float* Wuv  = (const float*)d_in[4];
  const float* Wo   = (const float*)d_in[5];
  float* out = (float*)d_out;

  char* ws = (char*)d_ws;
  bf16* Qb    = (bf16*)(ws + 0);              // 16 MB
  bf16* Kcat  = (bf16*)(ws + 16777216);       // 16 MB  (B*S, H*DH)
  bf16* VTcat = (bf16*)(ws + 33554432);       // 16 MB  (H*DH, B*S)
  bf16* xb    = (bf16*)(ws + 50331648);       // 16 MB (dead after qkv gemm)
  bf16* Op0   = (bf16*)(ws + 50331648);       // overlay: attn partial 0
  bf16* AO    = (bf16*)(ws + 50331648);       // overlay: combined attn out
  bf16* Ck    = (bf16*)(ws + 67108864);       //  4 MB (dead after up gemm)
  bf16* Op1   = (bf16*)(ws + 67108864);       // overlay: attn partial 1 (16 MB)
  bf16* Wqb   = (bf16*)(ws + 71303168);       //  8 MB (dead after qkv gemm)
  bf16* Wdkvb = (bf16*)(ws + 79691776);       //  2 MB (dead after qkv gemm)
  bf16* Wukb  = (bf16*)(ws + 81788928);       //  2 MB (dead after up gemm)
  bf16* Wuvb  = (bf16*)(ws + 83886080);       //  2 MB (dead after up gemm)
  float* ml0  = (float*)(ws + 83886080);      // overlay: 512 KB
  float* ml1  = (float*)(ws + 84410368);      // overlay: 512 KB
  bf16* Wob   = (bf16*)(ws + 85983232);       //  8 MB (live until out-proj)

  dim3 blk(256, 1, 1);

  // one fused fp32->bf16 conversion pass
  CvtArgs ca;
  ca.src[0] = x;    ca.dst[0] = xb;
  ca.src[1] = Wq;   ca.dst[1] = Wqb;
  ca.src[2] = Wdkv; ca.dst[2] = Wdkvb;
  ca.src[3] = Wuk;  ca.dst[3] = Wukb;
  ca.src[4] = Wuv;  ca.dst[4] = Wuvb;
  ca.src[5] = Wo;   ca.dst[5] = Wob;
  unsigned int n4[6] = { (unsigned)(Bc * Sc * DMc / 4), (unsigned)(DMc * DMc / 4),
                         (unsigned)(DLc * DMc / 4),     (unsigned)(Hc * DHc * DLc / 4),
                         (unsigned)(Hc * DHc * DLc / 4),(unsigned)(DMc * DMc / 4) };
  unsigned int acc = 0;
  for (int i = 0; i < 6; ++i) { ca.cum[i] = acc; acc += n4[i]; }
  ca.total4 = acc;
  cvt_all_kernel<<<2048, blk, 0, stream>>>(ca);

  // Q = x@Wq^T and Ckv = x@Wdkv^T, one launch (N = 2048 + 512)
  qkv_gemm_kernel<<<dim3(20, (Bc * Sc) / 128), blk, 0, stream>>>(xb, Wqb, Wdkvb, Qb, Ck);

  // K/V up-projections as one M=4096, N=4096, K=512 GEMM
  up_gemm_kernel<<<dim3(32, (Bc * Sc) / 128), blk, 0, stream>>>(Ck, Wukb, Wuvb, Kcat, VTcat);

  // attention, KV-split x2 (z = b*2 + split)
  mla_attn_kernel<<<dim3(Sc / 256, Hc, Bc * NSPL), dim3(512, 1, 1), 0, stream>>>(
      Qb, Kcat, VTcat, Op0, Op1, ml0, ml1);

  // combine partials into AO
  attn_combine_kernel<<<dim3((Bc * Sc * DMc / 8) / 256), blk, 0, stream>>>(
      Op0, Op1, ml0, ml1, AO);

  // out = AO @ Wo^T (fp32 out)
  gemm_bt_kernel<2><<<dim3(DMc / 128, (Bc * Sc) / 128), blk, 0, stream>>>(AO, Wob, out, DMc, DMc);
}

// Round 11
// 258.030 us; speedup vs baseline: 1.1039x; 1.1039x over previous
//
#include <hip/hip_runtime.h>
#include <hip/hip_bf16.h>

typedef __hip_bfloat16 bf16;
typedef __attribute__((ext_vector_type(8))) short short8v;
typedef __attribute__((ext_vector_type(4))) short short4v;
typedef __attribute__((ext_vector_type(4))) float f32x4;

#define MFMA_16x16x32(a, b, c) __builtin_amdgcn_mfma_f32_16x16x32_bf16((a), (b), (c), 0, 0, 0)

constexpr int Bc = 2, Sc = 2048, DMc = 2048, Hc = 16, DLc = 512, DHc = 128;

__device__ __forceinline__ void gload_lds16(const bf16* g, void* lds) {
  __builtin_amdgcn_global_load_lds(
      (const __attribute__((address_space(1))) void*)g,
      (__attribute__((address_space(3))) void*)lds, 16, 0, 0);
}

__device__ __forceinline__ unsigned short bf16bits(float f) {
  return __builtin_bit_cast(unsigned short, __float2bfloat16(f));
}

// ---------------------------------------------------------------------------
// fp32 -> bf16 conversion over 6 segments, one launch
// ---------------------------------------------------------------------------
struct CvtArgs {
  const float* src[6];
  bf16* dst[6];
  unsigned int cum[6];     // cumulative start (in 4-elem chunks)
  unsigned int total4;
};

__global__ __launch_bounds__(256) void cvt_all_kernel(CvtArgs a)
{
  unsigned int i = blockIdx.x * 256 + threadIdx.x;
  const unsigned int stride = gridDim.x * 256;
  for (; i < a.total4; i += stride) {
    int s = 0;
#pragma unroll
    for (int k = 1; k < 6; ++k) s += (i >= a.cum[k]) ? 1 : 0;
    unsigned int off = (i - a.cum[s]) * 4;
    float4 v = *(const float4*)(a.src[s] + off);
    short4v p;
    p[0] = (short)bf16bits(v.x);
    p[1] = (short)bf16bits(v.y);
    p[2] = (short)bf16bits(v.z);
    p[3] = (short)bf16bits(v.w);
    *(short4v*)(a.dst[s] + off) = p;
  }
}

// ---------------------------------------------------------------------------
// Generic 128x128 tile GEMM, BK=32, C = A * BT^T. EPI: 0 bf16 C, 1 bf16 C^T,
// 2 fp32 C.
// ---------------------------------------------------------------------------
template<int EPI>
__device__ __forceinline__ void gemm_tile_128(
    const bf16* __restrict__ A, const bf16* __restrict__ BT, void* __restrict__ Cv,
    int K, int ldc, int row0, int col0, bf16* As, bf16* Bs)
{
  const int tid = threadIdx.x;
  const int lane = tid & 63, wid = tid >> 6;
  const int wr = wid >> 1, wc = wid & 1;

  f32x4 acc[4][4] = {};

  const int srow = tid >> 2;
  const int scol = (tid & 3) * 8;
  const bf16* Ag = A + (size_t)(row0 + srow) * K + scol;
  const bf16* Bg = BT + (size_t)(col0 + srow) * K + scol;
  char* AsW = (char*)As + wid * 1024;
  char* BsW = (char*)Bs + wid * 1024;

  const int fr = lane & 15, fk = (lane >> 4) * 8;
  const bf16* aRd = As + (wr * 64 + fr) * 32 + fk;
  const bf16* bRd = Bs + (wc * 64 + fr) * 32 + fk;

  for (int k0 = 0; k0 < K; k0 += 32) {
    gload_lds16(Ag, AsW);
    gload_lds16(Ag + (size_t)64 * K, AsW + 4096);
    gload_lds16(Bg, BsW);
    gload_lds16(Bg + (size_t)64 * K, BsW + 4096);
    Ag += 32; Bg += 32;
    __syncthreads();
    short8v a[4], b[4];
#pragma unroll
    for (int m = 0; m < 4; ++m) a[m] = *(const short8v*)(aRd + m * 16 * 32);
#pragma unroll
    for (int n = 0; n < 4; ++n) b[n] = *(const short8v*)(bRd + n * 16 * 32);
#pragma unroll
    for (int m = 0; m < 4; ++m)
#pragma unroll
      for (int n = 0; n < 4; ++n)
        acc[m][n] = MFMA_16x16x32(a[m], b[n], acc[m][n]);
    __syncthreads();
  }

  const int crow = (lane >> 4) * 4, ccol = lane & 15;
  if (EPI == 0) {
    bf16* C = (bf16*)Cv;
#pragma unroll
    for (int m = 0; m < 4; ++m)
#pragma unroll
      for (int n = 0; n < 4; ++n) {
        bf16* Cp = C + (size_t)(row0 + wr * 64 + m * 16 + crow) * ldc
                     + col0 + wc * 64 + n * 16 + ccol;
#pragma unroll
        for (int r = 0; r < 4; ++r)
          Cp[(size_t)r * ldc] = __float2bfloat16(acc[m][n][r]);
      }
  } else if (EPI == 1) {
    bf16* C = (bf16*)Cv;
#pragma unroll
    for (int m = 0; m < 4; ++m)
#pragma unroll
      for (int n = 0; n < 4; ++n) {
        short4v pk;
#pragma unroll
        for (int r = 0; r < 4; ++r)
          pk[r] = (short)bf16bits(acc[m][n][r]);
        bf16* Cp = C + (size_t)(col0 + wc * 64 + n * 16 + ccol) * ldc
                     + row0 + wr * 64 + m * 16 + crow;
        *(short4v*)Cp = pk;
      }
  } else {
    float* C = (float*)Cv;
#pragma unroll
    for (int m = 0; m < 4; ++m)
#pragma unroll
      for (int n = 0; n < 4; ++n) {
        float* Cp = C + (size_t)(row0 + wr * 64 + m * 16 + crow) * ldc
                      + col0 + wc * 64 + n * 16 + ccol;
#pragma unroll
        for (int r = 0; r < 4; ++r)
          Cp[(size_t)r * ldc] = acc[m][n][r];
      }
  }
}

template<int EPI>
__global__ __launch_bounds__(256) void gemm_bt_kernel(
    const bf16* __restrict__ A, const bf16* __restrict__ BT, void* __restrict__ C,
    int K, int N)
{
  __shared__ bf16 As[128 * 32];
  __shared__ bf16 Bs[128 * 32];
  gemm_tile_128<EPI>(A, BT, C, K, N, blockIdx.y * 128, blockIdx.x * 128, As, Bs);
}

// Fused Q-proj + KV-down: N = 2048 (Wq) + 512 (Wdkv), K = 2048.
__global__ __launch_bounds__(256) void qkv_gemm_kernel(
    const bf16* __restrict__ xb, const bf16* __restrict__ Wqb,
    const bf16* __restrict__ Wdkvb, bf16* __restrict__ Qb, bf16* __restrict__ Ck)
{
  __shared__ bf16 As[128 * 32];
  __shared__ bf16 Bs[128 * 32];
  const int bx = blockIdx.x, row0 = blockIdx.y * 128;
  if (bx < 16)
    gemm_tile_128<0>(xb, Wqb, Qb, DMc, DMc, row0, bx * 128, As, Bs);
  else
    gemm_tile_128<0>(xb, Wdkvb, Ck, DMc, DLc, row0, (bx - 16) * 128, As, Bs);
}

// Fused K-up + V-up as ONE GEMM over stacked heads.
__global__ __launch_bounds__(256) void up_gemm_kernel(
    const bf16* __restrict__ Ck, const bf16* __restrict__ Wukb,
    const bf16* __restrict__ Wuvb, bf16* __restrict__ Kcat, bf16* __restrict__ VTcat)
{
  __shared__ bf16 As[128 * 32];
  __shared__ bf16 Bs[128 * 32];
  const int bx = blockIdx.x, row0 = blockIdx.y * 128;
  if (bx < 16)
    gemm_tile_128<0>(Ck, Wukb, Kcat, DLc, DMc, row0, bx * 128, As, Bs);
  else
    gemm_tile_128<1>(Ck, Wuvb, VTcat, DLc, Bc * Sc, row0, (bx - 16) * 128, As, Bs);
}

// ---------------------------------------------------------------------------
// Flash attention, swapped-QK^T design. mfma(K, Q) makes each lane own ONE
// q-row (q = fr): softmax state is lane-local scalars, P is 4-consecutive-t
// per lane -> packed b64 LDS writes (8/iter vs 32 b16), ONE lgkm sync/iter.
// 8 waves/block, 32 q-rows/wave, KV tile 64, single-barrier pipelined loop.
// No KV-split (co-residency unreachable: regs ~168/wave incl. accumulators).
// ---------------------------------------------------------------------------
constexpr int KVB = 64;
constexpr int NTT = Sc / KVB;   // 32 tiles
constexpr int VSTR = Bc * Sc;   // 4096

__global__ __launch_bounds__(512, 2) void mla_attn_kernel(
    const bf16* __restrict__ Q, const bf16* __restrict__ Kcat,
    const bf16* __restrict__ VTcat, bf16* __restrict__ O)
{
  __shared__ bf16 Ks[2][KVB * DHc];    // 16 KB each
  __shared__ bf16 Vs[2][DHc * KVB];    // 16 KB each
  __shared__ bf16 Pl[8 * 2 * 1024];    // per-(wave,mi) [16 q][64 t] (32 KB)

  const int tid = threadIdx.x, lane = tid & 63, wid = tid >> 6;
  const int h = blockIdx.y, b = blockIdx.z;
  const int q0 = blockIdx.x * 256 + wid * 32;
  const int fr = lane & 15, fg = lane >> 4;

  const bf16* Qp = Q + (size_t)(b * Sc + q0 + fr) * DMc + h * DHc + fg * 8;
  short8v qf[2][4];
#pragma unroll
  for (int mi = 0; mi < 2; ++mi)
#pragma unroll
    for (int kf = 0; kf < 4; ++kf)
      qf[mi][kf] = *(const short8v*)(Qp + (size_t)mi * 16 * DMc + kf * 32);

  const bf16* Kb = Kcat + (size_t)b * Sc * DMc + h * DHc;      // K[t][d], stride DMc
  const bf16* Vb = VTcat + (size_t)(h * DHc) * VSTR + b * Sc;  // VT[d][t], stride VSTR

  // staging addresses (inverse-swizzled global sources; LDS dest linear)
  const int krow = wid * 4 + fg;
  const int kcolB = (fr * 16) ^ ((krow & 7) << 4);
  const bf16* kp = Kb + (size_t)krow * DMc + (kcolB >> 1);
  const int vrow = wid * 8 + (lane >> 3);
  const int vcolB = ((lane & 7) * 16) ^ ((lane >> 3) << 4);
  const bf16* vp = Vb + (size_t)vrow * VSTR + (vcolB >> 1);

  auto STAGE = [&](int buf) {
    char* kd = (char*)(&Ks[buf][0]) + wid * 1024;
    gload_lds16(kp, kd);
    gload_lds16(kp + (size_t)32 * DMc, kd + 8192);
    char* vd = (char*)(&Vs[buf][0]) + wid * 1024;
    gload_lds16(vp, vd);
    gload_lds16(vp + (size_t)64 * VSTR, vd + 8192);
    kp += (size_t)KVB * DMc;
    vp += KVB;
  };

  f32x4 oacc[2][8] = {};
  float m_r[2], l_r[2], msc[2];
#pragma unroll
  for (int mi = 0; mi < 2; ++mi) { m_r[mi] = -1e30f; l_r[mi] = 0.f; msc[mi] = 0.f; }
  const float SCL2 = 0.12751650f;     // (1/sqrt(128)) * log2(e)
  const float THRraw = 47.0f;         // ~6 / SCL2 -> p bounded by 2^6

  STAGE(0);
  int cur = 0;
  char* Pb = (char*)Pl + wid * 4096;  // 2 KB per mi
  const int swz = (fr & 7) << 4;

  for (int it = 0; it < NTT; ++it) {
    asm volatile("s_waitcnt vmcnt(0)" ::: "memory");
    __builtin_amdgcn_s_barrier();
    asm volatile("" ::: "memory");
    if (it + 1 < NTT) STAGE(cur ^ 1);   // overwrite: safe, all waves past barrier
    asm volatile("" ::: "memory");

    // ---- QK^T (swapped: A = K, B = Q) -> sacc[t][q], lane owns q = fr ----
    f32x4 sacc[2][4] = {};
    __builtin_amdgcn_s_setprio(1);
#pragma unroll
    for (int nf = 0; nf < 4; ++nf) {
#pragma unroll
      for (int kf = 0; kf < 4; ++kf) {
        const bf16* kr = &Ks[cur][(nf * 16 + fr) * 128 +
                                  (((kf * 64 + fg * 16) ^ ((fr & 7) << 4)) >> 1)];
        short8v kfrag = *(const short8v*)kr;
        sacc[0][nf] = MFMA_16x16x32(kfrag, qf[0][kf], sacc[0][nf]);
        sacc[1][nf] = MFMA_16x16x32(kfrag, qf[1][kf], sacc[1][nf]);
      }
    }
    __builtin_amdgcn_s_setprio(0);

    // ---- lane-local online softmax with defer-max ----
    float pml[2];
    float dmax = -1e30f;
#pragma unroll
    for (int mi = 0; mi < 2; ++mi) {
      float pm = sacc[mi][0][0];
#pragma unroll
      for (int nf = 0; nf < 4; ++nf)
#pragma unroll
        for (int r = 0; r < 4; ++r)
          pm = fmaxf(pm, sacc[mi][nf][r]);
      pml[mi] = pm;
      dmax = fmaxf(dmax, pm - m_r[mi]);
    }

    if (!__all(dmax <= THRraw)) {
#pragma unroll
      for (int mi = 0; mi < 2; ++mi) {
        float red = pml[mi];
        red = fmaxf(red, __shfl_xor(red, 16, 64));
        red = fmaxf(red, __shfl_xor(red, 32, 64));
        float mnew = fmaxf(m_r[mi], red);
        float c = exp2f((m_r[mi] - mnew) * SCL2);
        m_r[mi] = mnew;
        msc[mi] = mnew * SCL2;
        l_r[mi] *= c;
        // oacc rows are q' = fg*4+r: pull corr from lane fr' = fg*4+r
        f32x4 cv;
#pragma unroll
        for (int r = 0; r < 4; ++r) cv[r] = __shfl(c, fg * 4 + r, 64);
#pragma unroll
        for (int df = 0; df < 8; ++df) oacc[mi][df] *= cv;
      }
    }

    // ---- P compute + packed b64 writes (per-wave private buffer) ----
#pragma unroll
    for (int mi = 0; mi < 2; ++mi) {
      char* Pm = Pb + mi * 2048;
#pragma unroll
      for (int nf = 0; nf < 4; ++nf) {
        float p0 = exp2f(__builtin_fmaf(sacc[mi][nf][0], SCL2, -msc[mi]));
        float p1 = exp2f(__builtin_fmaf(sacc[mi][nf][1], SCL2, -msc[mi]));
        float p2 = exp2f(__builtin_fmaf(sacc[mi][nf][2], SCL2, -msc[mi]));
        float p3 = exp2f(__builtin_fmaf(sacc[mi][nf][3], SCL2, -msc[mi]));
        l_r[mi] += (p0 + p1) + (p2 + p3);
        uint2 w;
        w.x = (unsigned)bf16bits(p0) | ((unsigned)bf16bits(p1) << 16);
        w.y = (unsigned)bf16bits(p2) | ((unsigned)bf16bits(p3) << 16);
        *(uint2*)(Pm + fr * 128 + ((nf * 32 + fg * 8) ^ swz)) = w;
      }
    }

    asm volatile("s_waitcnt lgkmcnt(0)" ::: "memory");
    __builtin_amdgcn_sched_barrier(0);

    short8v pa[2][2];
#pragma unroll
    for (int mi = 0; mi < 2; ++mi)
#pragma unroll
      for (int tf = 0; tf < 2; ++tf)
        pa[mi][tf] = *(const short8v*)(Pb + mi * 2048 + fr * 128 +
                                       ((tf * 64 + fg * 16) ^ swz));
    __builtin_amdgcn_sched_barrier(0);

    // ---- PV ----
    __builtin_amdgcn_s_setprio(1);
#pragma unroll
    for (int tf = 0; tf < 2; ++tf) {
#pragma unroll
      for (int df = 0; df < 8; ++df) {
        const bf16* vr = &Vs[cur][(df * 16 + fr) * 64 +
                                  (((tf * 64 + fg * 16) ^ ((fr & 7) << 4)) >> 1)];
        short8v vfrag = *(const short8v*)vr;
        oacc[0][df] = MFMA_16x16x32(pa[0][tf], vfrag, oacc[0][df]);
        oacc[1][df] = MFMA_16x16x32(pa[1][tf], vfrag, oacc[1][df]);
      }
    }
    __builtin_amdgcn_s_setprio(0);

    cur ^= 1;
  }

  // epilogue: reduce l across fg lanes, redistribute inv to oacc rows, store
#pragma unroll
  for (int mi = 0; mi < 2; ++mi) {
    float l = l_r[mi];
    l += __shfl_xor(l, 16, 64);
    l += __shfl_xor(l, 32, 64);
    float inv = 1.f / l;
    f32x4 iv;
#pragma unroll
    for (int r = 0; r < 4; ++r) iv[r] = __shfl(inv, fg * 4 + r, 64);
    bf16* Op = O + (size_t)(b * Sc + q0 + mi * 16 + fg * 4) * DMc + h * DHc + fr;
#pragma unroll
    for (int df = 0; df < 8; ++df)
#pragma unroll
      for (int r = 0; r < 4; ++r)
        Op[(size_t)r * DMc + df * 16] = __float2bfloat16(oacc[mi][df][r] * iv[r]);
  }
}

// ---------------------------------------------------------------------------
extern "C" void kernel_launch(void* const* d_in, const int* in_sizes, int n_in,
                              void* d_out, int out_size, void* d_ws, size_t ws_size,
                              hipStream_t stream)
{
  const float* x    = (const float*)d_in[0];
  const float* Wq   = (const float*)d_in[1];
  const float* Wdkv = (const float*)d_in[2];
  const float* Wuk  = (const float*)d_in[3];
  const float* Wuv  = (const float*)d_in[4];
  const float* Wo   = (const float*)d_in[5];
  float* out = (float*)d_out;

  char* ws = (char*)d_ws;
  bf16* Qb    = (bf16*)(ws + 0);              // 16 MB
  bf16* Kcat  = (bf16*)(ws + 16777216);       // 16 MB  (B*S, H*DH)
  bf16* VTcat = (bf16*)(ws + 33554432);       // 16 MB  (H*DH, B*S)
  bf16* xb    = (bf16*)(ws + 50331648);       // 16 MB (dead after qkv gemm)
  bf16* AO    = (bf16*)(ws + 50331648);       // overlay: attn output
  bf16* Ck    = (bf16*)(ws + 67108864);       //  4 MB
  bf16* Wqb   = (bf16*)(ws + 71303168);       //  8 MB
  bf16* Wdkvb = (bf16*)(ws + 79691776);       //  2 MB
  bf16* Wukb  = (bf16*)(ws + 81788928);       //  2 MB
  bf16* Wuvb  = (bf16*)(ws + 83886080);       //  2 MB
  bf16* Wob   = (bf16*)(ws + 85983232);       //  8 MB

  dim3 blk(256, 1, 1);

  // one fused fp32->bf16 conversion pass
  CvtArgs ca;
  ca.src[0] = x;    ca.dst[0] = xb;
  ca.src[1] = Wq;   ca.dst[1] = Wqb;
  ca.src[2] = Wdkv; ca.dst[2] = Wdkvb;
  ca.src[3] = Wuk;  ca.dst[3] = Wukb;
  ca.src[4] = Wuv;  ca.dst[4] = Wuvb;
  ca.src[5] = Wo;   ca.dst[5] = Wob;
  unsigned int n4[6] = { (unsigned)(Bc * Sc * DMc / 4), (unsigned)(DMc * DMc / 4),
                         (unsigned)(DLc * DMc / 4),     (unsigned)(Hc * DHc * DLc / 4),
                         (unsigned)(Hc * DHc * DLc / 4),(unsigned)(DMc * DMc / 4) };
  unsigned int acc = 0;
  for (int i = 0; i < 6; ++i) { ca.cum[i] = acc; acc += n4[i]; }
  ca.total4 = acc;
  cvt_all_kernel<<<2048, blk, 0, stream>>>(ca);

  // Q = x@Wq^T and Ckv = x@Wdkv^T, one launch (N = 2048 + 512)
  qkv_gemm_kernel<<<dim3(20, (Bc * Sc) / 128), blk, 0, stream>>>(xb, Wqb, Wdkvb, Qb, Ck);

  // K/V up-projections as one M=4096, N=4096, K=512 GEMM
  up_gemm_kernel<<<dim3(32, (Bc * Sc) / 128), blk, 0, stream>>>(Ck, Wukb, Wuvb, Kcat, VTcat);

  // attention (direct normalized output)
  mla_attn_kernel<<<dim3(Sc / 256, Hc, Bc), dim3(512, 1, 1), 0, stream>>>(
      Qb, Kcat, VTcat, AO);

  // out = AO @ Wo^T (fp32 out)
  gemm_bt_kernel<2><<<dim3(DMc / 128, (Bc * Sc) / 128), blk, 0, stream>>>(AO, Wob, out, DMc, DMc);
}

// Round 13
// 250.144 us; speedup vs baseline: 1.1387x; 1.0315x over previous
//
#include <hip/hip_runtime.h>
#include <hip/hip_bf16.h>

typedef __hip_bfloat16 bf16;
typedef __attribute__((ext_vector_type(8))) short short8v;
typedef __attribute__((ext_vector_type(4))) short short4v;
typedef __attribute__((ext_vector_type(4))) float f32x4;
typedef __attribute__((ext_vector_type(16))) float f32x16;
typedef __attribute__((ext_vector_type(4))) unsigned int uint4v;
typedef unsigned int u32;

#define MFMA_16x16x32(a, b, c) __builtin_amdgcn_mfma_f32_16x16x32_bf16((a), (b), (c), 0, 0, 0)
#define MFMA_32x32x16(a, b, c) __builtin_amdgcn_mfma_f32_32x32x16_bf16((a), (b), (c), 0, 0, 0)

constexpr int Bc = 2, Sc = 2048, DMc = 2048, Hc = 16, DLc = 512, DHc = 128;

__device__ __forceinline__ void gload_lds16(const bf16* g, void* lds) {
  __builtin_amdgcn_global_load_lds(
      (const __attribute__((address_space(1))) void*)g,
      (__attribute__((address_space(3))) void*)lds, 16, 0, 0);
}

__device__ __forceinline__ unsigned short bf16bits(float f) {
  return __builtin_bit_cast(unsigned short, __float2bfloat16(f));
}

// ---------------------------------------------------------------------------
// fp32 -> bf16 conversion over 6 segments, one launch
// ---------------------------------------------------------------------------
struct CvtArgs {
  const float* src[6];
  bf16* dst[6];
  unsigned int cum[6];
  unsigned int total4;
};

__global__ __launch_bounds__(256) void cvt_all_kernel(CvtArgs a)
{
  unsigned int i = blockIdx.x * 256 + threadIdx.x;
  const unsigned int stride = gridDim.x * 256;
  for (; i < a.total4; i += stride) {
    int s = 0;
#pragma unroll
    for (int k = 1; k < 6; ++k) s += (i >= a.cum[k]) ? 1 : 0;
    unsigned int off = (i - a.cum[s]) * 4;
    float4 v = *(const float4*)(a.src[s] + off);
    short4v p;
    p[0] = (short)bf16bits(v.x);
    p[1] = (short)bf16bits(v.y);
    p[2] = (short)bf16bits(v.z);
    p[3] = (short)bf16bits(v.w);
    *(short4v*)(a.dst[s] + off) = p;
  }
}

// ---------------------------------------------------------------------------
// Generic 128x128 tile GEMM, BK=32. EPI: 0 bf16 C, 1 bf16 C^T, 2 fp32 C.
// ---------------------------------------------------------------------------
template<int EPI>
__device__ __forceinline__ void gemm_tile_128(
    const bf16* __restrict__ A, const bf16* __restrict__ BT, void* __restrict__ Cv,
    int K, int ldc, int row0, int col0, bf16* As, bf16* Bs)
{
  const int tid = threadIdx.x;
  const int lane = tid & 63, wid = tid >> 6;
  const int wr = wid >> 1, wc = wid & 1;

  f32x4 acc[4][4] = {};

  const int srow = tid >> 2;
  const int scol = (tid & 3) * 8;
  const bf16* Ag = A + (size_t)(row0 + srow) * K + scol;
  const bf16* Bg = BT + (size_t)(col0 + srow) * K + scol;
  char* AsW = (char*)As + wid * 1024;
  char* BsW = (char*)Bs + wid * 1024;

  const int fr = lane & 15, fk = (lane >> 4) * 8;
  const bf16* aRd = As + (wr * 64 + fr) * 32 + fk;
  const bf16* bRd = Bs + (wc * 64 + fr) * 32 + fk;

  for (int k0 = 0; k0 < K; k0 += 32) {
    gload_lds16(Ag, AsW);
    gload_lds16(Ag + (size_t)64 * K, AsW + 4096);
    gload_lds16(Bg, BsW);
    gload_lds16(Bg + (size_t)64 * K, BsW + 4096);
    Ag += 32; Bg += 32;
    __syncthreads();
    short8v a[4], b[4];
#pragma unroll
    for (int m = 0; m < 4; ++m) a[m] = *(const short8v*)(aRd + m * 16 * 32);
#pragma unroll
    for (int n = 0; n < 4; ++n) b[n] = *(const short8v*)(bRd + n * 16 * 32);
#pragma unroll
    for (int m = 0; m < 4; ++m)
#pragma unroll
      for (int n = 0; n < 4; ++n)
        acc[m][n] = MFMA_16x16x32(a[m], b[n], acc[m][n]);
    __syncthreads();
  }

  const int crow = (lane >> 4) * 4, ccol = lane & 15;
  if (EPI == 0) {
    bf16* C = (bf16*)Cv;
#pragma unroll
    for (int m = 0; m < 4; ++m)
#pragma unroll
      for (int n = 0; n < 4; ++n) {
        bf16* Cp = C + (size_t)(row0 + wr * 64 + m * 16 + crow) * ldc
                     + col0 + wc * 64 + n * 16 + ccol;
#pragma unroll
        for (int r = 0; r < 4; ++r)
          Cp[(size_t)r * ldc] = __float2bfloat16(acc[m][n][r]);
      }
  } else if (EPI == 1) {
    bf16* C = (bf16*)Cv;
#pragma unroll
    for (int m = 0; m < 4; ++m)
#pragma unroll
      for (int n = 0; n < 4; ++n) {
        short4v pk;
#pragma unroll
        for (int r = 0; r < 4; ++r)
          pk[r] = (short)bf16bits(acc[m][n][r]);
        bf16* Cp = C + (size_t)(col0 + wc * 64 + n * 16 + ccol) * ldc
                     + row0 + wr * 64 + m * 16 + crow;
        *(short4v*)Cp = pk;
      }
  } else {
    float* C = (float*)Cv;
#pragma unroll
    for (int m = 0; m < 4; ++m)
#pragma unroll
      for (int n = 0; n < 4; ++n) {
        float* Cp = C + (size_t)(row0 + wr * 64 + m * 16 + crow) * ldc
                      + col0 + wc * 64 + n * 16 + ccol;
#pragma unroll
        for (int r = 0; r < 4; ++r)
          Cp[(size_t)r * ldc] = acc[m][n][r];
      }
  }
}

// XCD-contiguous remap (nwg % 8 == 0 for all our launches)
__device__ __forceinline__ int2 xcd_remap(int nx, int ny) {
  int flat = blockIdx.x + nx * blockIdx.y;
  int chunk = (nx * ny) >> 3;
  int role = (flat & 7) * chunk + (flat >> 3);
  return make_int2(role % nx, role / nx);
}

template<int EPI>
__global__ __launch_bounds__(256) void gemm_bt_kernel(
    const bf16* __restrict__ A, const bf16* __restrict__ BT, void* __restrict__ C,
    int K, int N)
{
  __shared__ bf16 As[128 * 32];
  __shared__ bf16 Bs[128 * 32];
  int2 bb = xcd_remap(gridDim.x, gridDim.y);
  gemm_tile_128<EPI>(A, BT, C, K, N, bb.y * 128, bb.x * 128, As, Bs);
}

// Fused Q-proj + KV-down: N = 2048 (Wq) + 512 (Wdkv), K = 2048.
__global__ __launch_bounds__(256) void qkv_gemm_kernel(
    const bf16* __restrict__ xb, const bf16* __restrict__ Wqb,
    const bf16* __restrict__ Wdkvb, bf16* __restrict__ Qb, bf16* __restrict__ Ck)
{
  __shared__ bf16 As[128 * 32];
  __shared__ bf16 Bs[128 * 32];
  int2 bb = xcd_remap(20, 32);
  const int bx = bb.x, row0 = bb.y * 128;
  if (bx < 16)
    gemm_tile_128<0>(xb, Wqb, Qb, DMc, DMc, row0, bx * 128, As, Bs);
  else
    gemm_tile_128<0>(xb, Wdkvb, Ck, DMc, DLc, row0, (bx - 16) * 128, As, Bs);
}

// Fused K-up + V-up as ONE GEMM over stacked heads.
__global__ __launch_bounds__(256) void up_gemm_kernel(
    const bf16* __restrict__ Ck, const bf16* __restrict__ Wukb,
    const bf16* __restrict__ Wuvb, bf16* __restrict__ Kcat, bf16* __restrict__ VTcat)
{
  __shared__ bf16 As[128 * 32];
  __shared__ bf16 Bs[128 * 32];
  int2 bb = xcd_remap(32, 32);
  const int bx = bb.x, row0 = bb.y * 128;
  if (bx < 16)
    gemm_tile_128<0>(Ck, Wukb, Kcat, DLc, DMc, row0, bx * 128, As, Bs);
  else
    gemm_tile_128<1>(Ck, Wuvb, VTcat, DLc, Bc * Sc, row0, (bx - 16) * 128, As, Bs);
}

// ---------------------------------------------------------------------------
// Flash attention v3: 32x32x16 MFMA, swapped operands, in-register softmax
// + cvt_pk/permlane32_swap P conversion (T12). NO P LDS roundtrip.
// v_permlane32_swap_b32 semantics (LLVM gfx950): vdst[32:63] <-> vsrc[0:31],
// so the completing-fragment call is swap(cA, cC) / swap(cB, cD)  [r12 bug:
// operands were reversed].
// Lane owns q = lane&31 for all t: softmax state = 3 scalars, oacc cols = q.
// K LDS: [64 t][256 B], swz(t) = ((t&7)<<4)^(((t>>3)&1)<<6)^(((t>>4)&1)<<7).
// V LDS: [64 rows][256 B], row r holds d=2r,2r+1; swz(r)=((r&7)<<4)^(((r>>3)&1)<<7).
// Both 2-way-max bank aliasing (free). Staging = linear dest + inverse-swz src.
// ---------------------------------------------------------------------------
constexpr int KVB = 64;
constexpr int NTT = Sc / KVB;   // 32 tiles
constexpr int VSTR = Bc * Sc;   // 4096

__global__ __launch_bounds__(512, 2) void mla_attn_kernel(
    const bf16* __restrict__ Q, const bf16* __restrict__ Kcat,
    const bf16* __restrict__ VTcat, bf16* __restrict__ O)
{
  __shared__ bf16 Ks[2][KVB * 128];    // 16 KB each ([64][256B])
  __shared__ bf16 Vs[2][64 * 128];     // 16 KB each ([64][256B], d-pairs)

  const int tid = threadIdx.x, lane = tid & 63, wid = tid >> 6;
  const int l31 = lane & 31, hi = lane >> 5;

  // XCD role remap: grid (8,16,2)
  const int flat = blockIdx.x + 8 * (blockIdx.y + 16 * blockIdx.z);
  const int role = (flat & 7) * 32 + (flat >> 3);
  const int qb = role & 7, h = (role >> 3) & 15, b = role >> 7;
  const int q0 = qb * 256 + wid * 32;

  // Q B-frags: lane holds Q[q0+l31][kk*16 + hi*8 + j]
  const bf16* Qp = Q + (size_t)(b * Sc + q0 + l31) * DMc + h * DHc + hi * 8;
  short8v qf[8];
#pragma unroll
  for (int kk = 0; kk < 8; ++kk) qf[kk] = *(const short8v*)(Qp + kk * 16);

  const bf16* Kb = Kcat + (size_t)b * Sc * DMc + h * DHc;      // K[t][d], stride DMc
  const bf16* Vb = VTcat + (size_t)(h * DHc) * VSTR + b * Sc;  // VT[d][t], stride VSTR

  // ---- staging source addresses (inverse-swizzled; LDS dest linear) ----
  const int srow = tid >> 4;            // 0..31
  const int scol = (tid & 15) * 16;     // 0..240
  const int swzKs = ((srow & 7) << 4) ^ (((srow >> 3) & 1) << 6) ^ (((srow >> 4) & 1) << 7);
  const bf16* kp = Kb + (size_t)srow * DMc + (((scol ^ swzKs) & 255) >> 1);
  const int swzVs = ((srow & 7) << 4) ^ (((srow >> 3) & 1) << 7);
  const int vcp = scol ^ swzVs;
  const bf16* vp = Vb + (size_t)(2 * srow + (vcp >> 7)) * VSTR + ((vcp & 127) >> 1);

  auto STAGE = [&](int buf, int t0) {
    char* kd = (char*)(&Ks[buf][0]) + wid * 1024;
    const bf16* k0 = kp + (size_t)t0 * DMc;
    gload_lds16(k0, kd);
    gload_lds16(k0 + (size_t)32 * DMc, kd + 8192);
    char* vd = (char*)(&Vs[buf][0]) + wid * 1024;
    const bf16* v0 = vp + t0;
    gload_lds16(v0, vd);
    gload_lds16(v0 + (size_t)64 * VSTR, vd + 8192);
  };

  // read-side swizzles (lane consts)
  const int swzR = ((l31 & 7) << 4) ^ (((l31 >> 3) & 1) << 6) ^ (((l31 >> 4) & 1) << 7);
  const int swzVR = (((l31 >> 1) & 7) << 4) ^ (((l31 >> 4) & 1) << 7);

  f32x16 oacc[4] = {};
  float m_r = -1e30f, l_r = 0.f, msc = 0.f;
  const float SCL2 = 0.12751650f;     // (1/sqrt(128)) * log2(e)
  const float THRraw = 47.0f;         // ~6 / SCL2 -> p bounded by 2^6

  STAGE(0, 0);
  int cur = 0;

  for (int it = 0; it < NTT; ++it) {
    asm volatile("s_waitcnt vmcnt(0)" ::: "memory");
    __builtin_amdgcn_s_barrier();
    asm volatile("" ::: "memory");
    if (it + 1 < NTT) STAGE(cur ^ 1, (it + 1) * KVB);
    asm volatile("" ::: "memory");

    // ---- QK^T: S[t][q] = K x Q^T, 2 t-tiles x 8 d-subtiles ----
    f32x16 s0 = {}, s1 = {};
    const char* Kc = (const char*)(&Ks[cur][0]);
    __builtin_amdgcn_s_setprio(1);
#pragma unroll
    for (int kk = 0; kk < 8; ++kk) {
      const int cb = (kk * 32 + hi * 16) ^ swzR;
      short8v k0 = *(const short8v*)(Kc + l31 * 256 + cb);
      short8v k1 = *(const short8v*)(Kc + (32 + l31) * 256 + cb);
      s0 = MFMA_32x32x16(k0, qf[kk], s0);
      s1 = MFMA_32x32x16(k1, qf[kk], s1);
    }
    __builtin_amdgcn_s_setprio(0);

    // ---- lane-local online softmax with defer-max ----
    float pm = s0[0];
#pragma unroll
    for (int i = 1; i < 16; ++i) pm = fmaxf(pm, s0[i]);
#pragma unroll
    for (int i = 0; i < 16; ++i) pm = fmaxf(pm, s1[i]);

    if (!__all(pm - m_r <= THRraw)) {
      float red = fmaxf(pm, __shfl_xor(pm, 32, 64));
      float mnew = fmaxf(m_r, red);
      float c = exp2f((m_r - mnew) * SCL2);
      m_r = mnew;
      msc = mnew * SCL2;
      l_r *= c;
#pragma unroll
      for (int db = 0; db < 4; ++db) oacc[db] *= c;
    }

    // ---- P = exp2(S*SCL2 - msc) -> bf16 B-frags via cvt_pk + permlane ----
    short8v pf[4];
#pragma unroll
    for (int tt = 0; tt < 2; ++tt) {
      const f32x16& s = tt ? s1 : s0;
#pragma unroll
      for (int half = 0; half < 2; ++half) {
        float e0 = exp2f(__builtin_fmaf(s[half * 8 + 0], SCL2, -msc));
        float e1 = exp2f(__builtin_fmaf(s[half * 8 + 1], SCL2, -msc));
        float e2 = exp2f(__builtin_fmaf(s[half * 8 + 2], SCL2, -msc));
        float e3 = exp2f(__builtin_fmaf(s[half * 8 + 3], SCL2, -msc));
        float e4 = exp2f(__builtin_fmaf(s[half * 8 + 4], SCL2, -msc));
        float e5 = exp2f(__builtin_fmaf(s[half * 8 + 5], SCL2, -msc));
        float e6 = exp2f(__builtin_fmaf(s[half * 8 + 6], SCL2, -msc));
        float e7 = exp2f(__builtin_fmaf(s[half * 8 + 7], SCL2, -msc));
        l_r += ((e0 + e1) + (e2 + e3)) + ((e4 + e5) + (e6 + e7));
        u32 cA, cB, cC, cD;
        asm("v_cvt_pk_bf16_f32 %0, %1, %2" : "=v"(cA) : "v"(e0), "v"(e1));
        asm("v_cvt_pk_bf16_f32 %0, %1, %2" : "=v"(cB) : "v"(e2), "v"(e3));
        asm("v_cvt_pk_bf16_f32 %0, %1, %2" : "=v"(cC) : "v"(e4), "v"(e5));
        asm("v_cvt_pk_bf16_f32 %0, %1, %2" : "=v"(cD) : "v"(e6), "v"(e7));
        // HW: vdst[32:63] <-> vsrc[0:31]. swap(cA,cC): cA.hi <- cC.lo,
        // cC.lo <- cA.hi  => cA = {t0t1|t8t9}, cC = {t4t5|t12t13}.
        asm volatile("v_permlane32_swap_b32 %0, %1" : "+v"(cA), "+v"(cC));
        asm volatile("v_permlane32_swap_b32 %0, %1" : "+v"(cB), "+v"(cD));
        uint4v w;
        w[0] = cA; w[1] = cB; w[2] = cC; w[3] = cD;
        pf[tt * 2 + half] = __builtin_bit_cast(short8v, w);
      }
    }

    // ---- PV: O[d][q] += V^T x P ----
    const char* Vc = (const char*)(&Vs[cur][0]);
    __builtin_amdgcn_s_setprio(1);
#pragma unroll
    for (int db = 0; db < 4; ++db) {
      const int vrow = (db * 16 + (l31 >> 1)) * 256;
#pragma unroll
      for (int ts = 0; ts < 4; ++ts) {
        const int cb = ((l31 & 1) * 128 + ts * 32 + hi * 16) ^ swzVR;
        short8v vf = *(const short8v*)(Vc + vrow + cb);
        oacc[db] = MFMA_32x32x16(vf, pf[ts], oacc[db]);
      }
    }
    __builtin_amdgcn_s_setprio(0);

    cur ^= 1;
  }

  // ---- epilogue: normalize and store ----
  float l = l_r + __shfl_xor(l_r, 32, 64);
  float inv = 1.f / l;
  bf16* Op = O + (size_t)(b * Sc + q0 + l31) * DMc + h * DHc + hi * 4;
#pragma unroll
  for (int db = 0; db < 4; ++db) {
#pragma unroll
    for (int rq = 0; rq < 4; ++rq) {
      short4v pk;
#pragma unroll
      for (int r = 0; r < 4; ++r)
        pk[r] = (short)bf16bits(oacc[db][rq * 4 + r] * inv);
      *(short4v*)(Op + db * 32 + rq * 8) = pk;
    }
  }
}

// ---------------------------------------------------------------------------
extern "C" void kernel_launch(void* const* d_in, const int* in_sizes, int n_in,
                              void* d_out, int out_size, void* d_ws, size_t ws_size,
                              hipStream_t stream)
{
  const float* x    = (const float*)d_in[0];
  const float* Wq   = (const float*)d_in[1];
  const float* Wdkv = (const float*)d_in[2];
  const float* Wuk  = (const float*)d_in[3];
  const float* Wuv  = (const float*)d_in[4];
  const float* Wo   = (const float*)d_in[5];
  float* out = (float*)d_out;

  char* ws = (char*)d_ws;
  bf16* Qb    = (bf16*)(ws + 0);              // 16 MB
  bf16* Kcat  = (bf16*)(ws + 16777216);       // 16 MB  (B*S, H*DH)
  bf16* VTcat = (bf16*)(ws + 33554432);       // 16 MB  (H*DH, B*S)
  bf16* xb    = (bf16*)(ws + 50331648);       // 16 MB (dead after qkv gemm)
  bf16* AO    = (bf16*)(ws + 50331648);       // overlay: attn output
  bf16* Ck    = (bf16*)(ws + 67108864);       //  4 MB
  bf16* Wqb   = (bf16*)(ws + 71303168);       //  8 MB
  bf16* Wdkvb = (bf16*)(ws + 79691776);       //  2 MB
  bf16* Wukb  = (bf16*)(ws + 81788928);       //  2 MB
  bf16* Wuvb  = (bf16*)(ws + 83886080);       //  2 MB
  bf16* Wob   = (bf16*)(ws + 85983232);       //  8 MB

  dim3 blk(256, 1, 1);

  CvtArgs ca;
  ca.src[0] = x;    ca.dst[0] = xb;
  ca.src[1] = Wq;   ca.dst[1] = Wqb;
  ca.src[2] = Wdkv; ca.dst[2] = Wdkvb;
  ca.src[3] = Wuk;  ca.dst[3] = Wukb;
  ca.src[4] = Wuv;  ca.dst[4] = Wuvb;
  ca.src[5] = Wo;   ca.dst[5] = Wob;
  unsigned int n4[6] = { (unsigned)(Bc * Sc * DMc / 4), (unsigned)(DMc * DMc / 4),
                         (unsigned)(DLc * DMc / 4),     (unsigned)(Hc * DHc * DLc / 4),
                         (unsigned)(Hc * DHc * DLc / 4),(unsigned)(DMc * DMc / 4) };
  unsigned int acc = 0;
  for (int i = 0; i < 6; ++i) { ca.cum[i] = acc; acc += n4[i]; }
  ca.total4 = acc;
  cvt_all_kernel<<<2048, blk, 0, stream>>>(ca);

  // Q = x@Wq^T and Ckv = x@Wdkv^T (N = 2048 + 512)
  qkv_gemm_kernel<<<dim3(20, (Bc * Sc) / 128), blk, 0, stream>>>(xb, Wqb, Wdkvb, Qb, Ck);

  // K/V up-projections as one M=4096, N=4096, K=512 GEMM
  up_gemm_kernel<<<dim3(32, (Bc * Sc) / 128), blk, 0, stream>>>(Ck, Wukb, Wuvb, Kcat, VTcat);

  // attention
  mla_attn_kernel<<<dim3(Sc / 256, Hc, Bc), dim3(512, 1, 1), 0, stream>>>(
      Qb, Kcat, VTcat, AO);

  // out = AO @ Wo^T (fp32 out)
  gemm_bt_kernel<2><<<dim3(DMc / 128, (Bc * Sc) / 128), blk, 0, stream>>>(AO, Wob, out, DMc, DMc);
}